// Round 8
// baseline (330.460 us; speedup 1.0000x reference)
//
#include <hip/hip_runtime.h>
#include <stdint.h>

#define C_   128
#define HW_  16384
#define CHW_ (C_*HW_)
#define N_   65536
#define E_   11
#define K_   6
#define HID_ 512

typedef __attribute__((ext_vector_type(8))) _Float16 half8;
typedef __attribute__((ext_vector_type(2))) _Float16 h2;
typedef __attribute__((ext_vector_type(2))) __fp16 fp16v2;
typedef __attribute__((ext_vector_type(16))) float float16v;
typedef __attribute__((ext_vector_type(2))) unsigned uint2v;

// async global->LDS, 16B per lane; LDS dst is wave-uniform base + lane*16
#define GLD(g, s) __builtin_amdgcn_global_load_lds( \
    (const __attribute__((address_space(1))) unsigned int*)(uintptr_t)(g), \
    (__attribute__((address_space(3))) unsigned int*)(unsigned int)(uintptr_t)(s), 16, 0, 0)

// f32x2 -> packed f16 pair (RTZ), bitcast to _Float16 vector
__device__ __forceinline__ h2 pkrtz(float a, float b){
  union { fp16v2 f; h2 h; } u;
  u.f = __builtin_amdgcn_cvt_pkrtz(a, b);
  return u.h;
}
// gelu(v)*wr on packed f16 pairs: odd deg-7 erf fit (|t|<=2.5, max err ~2.4e-3).
__device__ __forceinline__ h2 gelu2h(h2 v, h2 wr2){
  h2 u = v * v;
  h2 s = u * (h2)(_Float16)(-0.00076957f) + (h2)(_Float16)(0.0147811f);
  s = s * u + (h2)(_Float16)(-0.126434f);
  s = s * u + (h2)(_Float16)(0.795742f);
  h2 p = v * s;
  h2 phi = p * (h2)(_Float16)(0.5f) + (h2)(_Float16)(0.5f);
  return v * wr2 * phi;
}
// lane l <-> lane l^32 exchange: a' = [a_lo, b_lo], b' = [a_hi, b_hi]
__device__ __forceinline__ void pswap32(unsigned &a, unsigned &b){
#if __has_builtin(__builtin_amdgcn_permlane32_swap)
  uint2v r = __builtin_amdgcn_permlane32_swap(a, b, false, false);
  a = r.x; b = r.y;
#else
  asm volatile("v_permlane32_swap_b32 %0, %1" : "+v"(a), "+v"(b));
#endif
}

// ---------------- build MFMA-frag-ordered f16 weight image (32x32x16 frags) ----
// record i = e*16+hc (16KB): [0,8KB) W1 A-frags kc=0..7: lane l holds
//   w1[e][hc*32+(l&31)][kc*16+(l>>5)*8 + j], j=0..7
// [8KB,16KB): W2 A-frags (ct*2+kc2): lane l: w2[e][ct*32+(l&31)][hc*32+kc2*16+(l>>5)*8+j]
// plus b1h image: per record 32 f16 in hacc-register order (j-order, hi-major).
// Also zeroes the 22 aux accumulators (k_ffn atomically adds; stream-ordered).
__global__ __launch_bounds__(256) void k_convert(const float* __restrict__ w1,
                                                 const float* __restrict__ w2,
                                                 const float* __restrict__ b1,
                                                 unsigned short* __restrict__ wimg,
                                                 unsigned short* __restrict__ b1h,
                                                 float* __restrict__ auxsum){
  int t = blockIdx.x * 256 + threadIdx.x;
  if (t < 23) auxsum[t] = 0.0f;          // 22 aux accumulators (+1 spare)
  if (t >= 185856) return;
  if (t >= 180224){                       // b1h: 176 recs x 32 f16
    int t2 = t - 180224;
    int rec = t2 >> 5, j5 = t2 & 31;
    int hi = j5 >> 4, j = j5 & 15;
    int e = rec >> 4, hc = rec & 15;
    int row = (j & 3) + 8 * (j >> 2) + 4 * hi;
    union { _Float16 h; unsigned short u; } cv;
    cv.h = (_Float16)b1[e * 512 + hc * 32 + row];
    b1h[rec * 32 + j5] = cv.u;
    return;
  }
  const float* src;
  size_t dst;
  if (t < 90112){
    int e = t >> 13, hid = (t >> 4) & 511, c8 = t & 15;
    src = w1 + (size_t)t * 8;
    int rec = e * 16 + (hid >> 5);
    int kc = c8 >> 1, half = c8 & 1;
    int l = (hid & 31) | (half << 5);
    dst = (size_t)rec * 8192 + kc * 512 + l * 8;
  } else {
    int u = t - 90112;
    int e = u >> 13, cc = (u >> 6) & 127, hd8 = u & 63;
    src = w2 + (size_t)u * 8;
    int rec = e * 16 + (hd8 >> 2);
    int kc2 = (hd8 >> 1) & 1, half = hd8 & 1, ct = cc >> 5;
    int l = (cc & 31) | (half << 5);
    dst = (size_t)rec * 8192 + 4096 + (ct * 2 + kc2) * 512 + l * 8;
  }
  float4 a = *(const float4*)src, b = *(const float4*)(src + 4);
  union { _Float16 h[8]; uint4 v; } u4;
  u4.h[0] = (_Float16)a.x; u4.h[1] = (_Float16)a.y;
  u4.h[2] = (_Float16)a.z; u4.h[3] = (_Float16)a.w;
  u4.h[4] = (_Float16)b.x; u4.h[5] = (_Float16)b.y;
  u4.h[6] = (_Float16)b.z; u4.h[7] = (_Float16)b.w;
  *(uint4*)(wimg + dst) = u4.v;
}

// ---------------- fused MoE: transpose+router prologue + r7 FFN ring loop ------
// 512 thr = 8 waves; 256 px/block; grid 256 = 1 block/CU (2 waves/SIMD).
// PROLOGUE (new): each block transposes ITS 256 px (4 rounds of 64 px through
// a tt[64][130] LDS tile in the otherwise-idle 64KB smem), writes f16 xcl +
// router mask for its own pixels (same-block L2-hot, ~fresh lines so no L1
// staleness), LDS-accumulates router stats, 22 device atomicAdds at the end.
// This deletes the standalone prep kernel (~90us of un-countered tail) and
// makes its true cost visible inside k_ffn's counters.
// MAIN LOOP: r7-verbatim (207us-proven). Aux-loss finalized by tiny k_aux.
__global__ __launch_bounds__(512, 2) void k_ffn(const float* __restrict__ x,
                                                const float* __restrict__ gw,
                                                const float* __restrict__ gb,
                                                unsigned short* __restrict__ xcl,
                                                float* __restrict__ mask,
                                                const unsigned short* __restrict__ wimg,
                                                const unsigned short* __restrict__ b1h,
                                                const float* __restrict__ b2,
                                                float* __restrict__ auxsum,
                                                float* __restrict__ y){
  __shared__ unsigned char smem[65536];
  __shared__ int b2f;
  int tid = threadIdx.x;
  int w = tid >> 6, l = tid & 63;
  int l31 = l & 31, hi = l >> 5;
  int hi4 = hi * 4;
  int pix0 = blockIdx.x * 256;
  int off = (blockIdx.x % 11) * 16;
  const unsigned char* wimgB = (const unsigned char*)wimg;
  const unsigned char* b1hB  = (const unsigned char*)b1h;

  if (tid == 0) b2f = 0;

  // ======== fused prep prologue: smem hosts tt/g/stats before W staging ========
  {
    float* tt  = (float*)smem;                  // [64][130] f32 = 33,280B
    float* g   = (float*)(smem + 33280);        // [11][128] = 5,632B
    float* gbs = (float*)(smem + 38912);        // [11]
    float* ap  = (float*)(smem + 38976);        // [11]
    float* al  = (float*)(smem + 39040);        // [11]

    for (int i = tid; i < E_ * C_; i += 512) g[i] = gw[i];
    if (tid < E_){ gbs[tid] = gb[tid]; ap[tid] = 0.f; al[tid] = 0.f; }

    #pragma unroll 1
    for (int rr = 0; rr < 4; ++rr){
      int pixc = pix0 + rr * 64;
      const float* xb = x + (size_t)(pixc >> 14) * CHW_ + (pixc & 16383);
      __syncthreads();                    // g ready (rr=0); tt free (rr>0)
      // transpose-in: 8192 elems / 512 thr = 16 coalesced scalar loads each
      #pragma unroll
      for (int it = 0; it < 16; ++it){
        int flat = it * 512 + tid;
        int c = flat >> 6, p = flat & 63;
        tt[p * 130 + c] = xb[(size_t)c * HW_ + p];
      }
      __syncthreads();                    // tt ready
      // pack to f16 xcl: 4096 u32 / 512 thr = 8 each
      #pragma unroll
      for (int it = 0; it < 8; ++it){
        int u = it * 512 + tid;
        int p = u >> 6, cc = u & 63;
        union { h2 h; unsigned u32; } pv;
        pv.h = pkrtz(tt[p * 130 + 2 * cc], tt[p * 130 + 2 * cc + 1]);
        ((unsigned*)xcl)[(size_t)(pixc + p) * 64 + cc] = pv.u32;
      }
      // router: threads 0..255, 4 per pixel (same wave quad), 32 ch each
      if (tid < 256){
        int p = tid >> 2, t4 = tid & 3;
        float lg[E_];
        #pragma unroll
        for (int e = 0; e < E_; ++e) lg[e] = (t4 == 0) ? gbs[e] : 0.f;
        const float2* ttrow = (const float2*)(tt + p * 130 + t4 * 32);
        #pragma unroll 4
        for (int j2 = 0; j2 < 16; ++j2){
          float2 xv = ttrow[j2];
          #pragma unroll
          for (int e = 0; e < E_; ++e){
            float2 gv = *(const float2*)(g + e * C_ + t4 * 32 + j2 * 2);
            lg[e] = fmaf(xv.x, gv.x, lg[e]);
            lg[e] = fmaf(xv.y, gv.y, lg[e]);
          }
        }
        #pragma unroll
        for (int e = 0; e < E_; ++e){
          lg[e] += __shfl_xor(lg[e], 1, 64);
          lg[e] += __shfl_xor(lg[e], 2, 64);
        }
        float mx = lg[0];
        #pragma unroll
        for (int e = 1; e < E_; ++e) mx = fmaxf(mx, lg[e]);
        float pr[E_]; float s = 0.f;
        #pragma unroll
        for (int e = 0; e < E_; ++e){ pr[e] = expf(lg[e] - mx); s += pr[e]; }
        float inv = 1.0f / s;
        #pragma unroll
        for (int e = 0; e < E_; ++e) pr[e] *= inv;

        unsigned selmask = 0; float wsum = 0.f;
        for (int k = 0; k < K_; ++k){
          float bv = -1.f; int bi = 0;
          #pragma unroll
          for (int e = 0; e < E_; ++e){
            bool better = (((selmask >> e) & 1u) == 0u) && (pr[e] > bv);
            bv = better ? pr[e] : bv;
            bi = better ? e : bi;
          }
          selmask |= 1u << bi; wsum += bv;
        }
        float invw = 1.0f / wsum;
        if (t4 == 0){
          int pix = pixc + p;
          #pragma unroll
          for (int e = 0; e < E_; ++e){
            bool sel = (selmask >> e) & 1u;
            mask[(size_t)pix * E_ + e] = sel ? pr[e] * invw : 0.f;
            atomicAdd(&ap[e], pr[e]);
            if (sel) atomicAdd(&al[e], 1.0f);
          }
        }
      }
    }
    __syncthreads();                      // rounds done; ap/al final; xcl drained
    if (tid < E_){
      atomicAdd(&auxsum[tid], ap[tid]);         // device-scope, zeroed by k_convert
      atomicAdd(&auxsum[E_ + tid], al[tid]);
    }
  }
  // ======== end prologue; smem now free for W double-buffer ====================

  // X B-frags (32x32x16 f16): lane l: X^T[c = kc*16 + hi*8 + j][pix = 32w + l31]
  half8 Xf[8];
  {
    const unsigned short* xrow = xcl + ((size_t)(pix0 + w * 32 + l31) << 7) + hi * 8;
    #pragma unroll
    for (int kc = 0; kc < 8; ++kc)
      Xf[kc] = *(const half8*)(xrow + kc * 16);
  }

  uint4 bhA[4], bhB[4];
  const size_t mrow = (size_t)(pix0 + w * 32 + l31) * 11;

  // prologue: stage super-iter 0 (records off, off+1) into buffer 0.
  // GLDs first, then bias loads (vmcnt-order discipline).
  {
    #pragma unroll
    for (int k = 0; k < 2; ++k){
      int rec = off + k;
      const unsigned char* gs = wimgB + (size_t)rec * 16384 + w * 2048 + l * 16;
      unsigned char* dst = smem + k * 16384 + w * 2048;
      GLD(gs, dst);
      GLD(gs + 1024, dst + 1024);
    }
    #pragma unroll
    for (int k = 0; k < 2; ++k){
      const unsigned char* bp = b1hB + (off + k) * 64 + hi * 32;
      bhA[2 * k]     = *(const uint4*)(bp);
      bhA[2 * k + 1] = *(const uint4*)(bp + 16);
    }
  }
  // routing-weight prefetch pipeline: wrn holds expert (off>>4)'s weight
  float wrn = mask[mrow + (off >> 4)];
  __syncthreads();   // full drain: buffer 0 + regs ready

  float16v facc[4];
  #pragma unroll
  for (int ct = 0; ct < 4; ++ct) facc[ct] = (float16v)0.0f;
  h2 wr2 = (h2)(_Float16)0.0f;

  // one record's compute: GEMM1(LDS W1) -> gelu/pack/pswap -> GEMM2(LDS W2)
#define REC_BODY(WB, BH0, BH1)                                                      \
  {                                                                                 \
    float16v hacc_ = (float16v)0.0f;                                                \
    _Pragma("unroll")                                                               \
    for (int kc_ = 0; kc_ < 8; ++kc_){                                              \
      half8 a_ = *(const half8*)((WB) + kc_ * 1024 + l * 16);                       \
      hacc_ = __builtin_amdgcn_mfma_f32_32x32x16_f16(a_, Xf[kc_], hacc_, 0, 0, 0);  \
    }                                                                               \
    union { uint4 v[2]; h2 h[8]; } bu_;                                             \
    bu_.v[0] = BH0; bu_.v[1] = BH1;                                                 \
    unsigned pd_[8];                                                                \
    _Pragma("unroll")                                                               \
    for (int k_ = 0; k_ < 8; ++k_){                                                 \
      h2 v_ = pkrtz(hacc_[2 * k_], hacc_[2 * k_ + 1]);                              \
      v_ = v_ + bu_.h[k_];                                                          \
      union { h2 h; unsigned u; } g_;                                               \
      g_.h = gelu2h(v_, wr2);                                                       \
      pd_[k_] = g_.u;                                                               \
    }                                                                               \
    pswap32(pd_[0], pd_[2]); pswap32(pd_[1], pd_[3]);                               \
    pswap32(pd_[4], pd_[6]); pswap32(pd_[5], pd_[7]);                               \
    union { unsigned u[4]; half8 s; } cv0_, cv1_;                                   \
    cv0_.u[0] = pd_[0]; cv0_.u[1] = pd_[1]; cv0_.u[2] = pd_[2]; cv0_.u[3] = pd_[3]; \
    cv1_.u[0] = pd_[4]; cv1_.u[1] = pd_[5]; cv1_.u[2] = pd_[6]; cv1_.u[3] = pd_[7]; \
    _Pragma("unroll")                                                               \
    for (int ct_ = 0; ct_ < 4; ++ct_){                                              \
      half8 a0_ = *(const half8*)((WB) + 8192 + (ct_ * 2 + 0) * 1024 + l * 16);     \
      half8 a1_ = *(const half8*)((WB) + 8192 + (ct_ * 2 + 1) * 1024 + l * 16);     \
      facc[ct_] = __builtin_amdgcn_mfma_f32_32x32x16_f16(a0_, cv0_.s, facc[ct_], 0, 0, 0); \
      facc[ct_] = __builtin_amdgcn_mfma_f32_32x32x16_f16(a1_, cv1_.s, facc[ct_], 0, 0, 0); \
    }                                                                               \
  }

#define SUPER_BODY(J, BHC, BHL)                                                     \
  {                                                                                 \
    asm volatile("s_waitcnt vmcnt(4)" ::: "memory");                                \
    __builtin_amdgcn_s_barrier();                                                   \
    __builtin_amdgcn_sched_barrier(0);                                              \
    /* prefetch super-iter J+1: 4 GLDs FIRST, then 4 bias loads; wrap benign */     \
    {                                                                               \
      unsigned char* dbuf_ = smem + ((((J) + 1) & 1) << 15);                        \
      _Pragma("unroll")                                                             \
      for (int k_ = 0; k_ < 2; ++k_){                                               \
        int rn_ = 2 * (J) + 2 + k_ + off; if (rn_ >= 176) rn_ -= 176;               \
        const unsigned char* gs_ = wimgB + (size_t)rn_ * 16384 + w * 2048 + l * 16; \
        unsigned char* dst_ = dbuf_ + k_ * 16384 + w * 2048;                        \
        GLD(gs_, dst_);                                                             \
        GLD(gs_ + 1024, dst_ + 1024);                                               \
      }                                                                             \
      __builtin_amdgcn_sched_barrier(0);                                            \
      _Pragma("unroll")                                                             \
      for (int k_ = 0; k_ < 2; ++k_){                                               \
        int rn_ = 2 * (J) + 2 + k_ + off; if (rn_ >= 176) rn_ -= 176;               \
        const unsigned char* bp_ = b1hB + rn_ * 64 + hi * 32;                       \
        BHL[2 * k_]     = *(const uint4*)(bp_);                                     \
        BHL[2 * k_ + 1] = *(const uint4*)(bp_ + 16);                                \
      }                                                                             \
    }                                                                               \
    __builtin_amdgcn_sched_barrier(0);                                              \
    if (((J) & 7) == 0){   /* expert switch every 8 super-iters (uniform) */        \
      _Float16 wh_ = (_Float16)wrn;                                                 \
      wr2 = (h2){wh_, wh_};                                                         \
      int rn_ = 2 * (J) + 16 + off; if (rn_ >= 176) rn_ -= 176;                     \
      wrn = mask[mrow + (rn_ >> 4)];                                                \
    }                                                                               \
    const unsigned char* wb_ = smem + (((J) & 1) << 15);                            \
    REC_BODY(wb_, BHC[0], BHC[1]);                                                  \
    REC_BODY(wb_ + 16384, BHC[2], BHC[3]);                                          \
  }

  #pragma unroll 1
  for (int jj = 0; jj < 44; ++jj){
    SUPER_BODY(2 * jj,     bhA, bhB);
    SUPER_BODY(2 * jj + 1, bhB, bhA);
  }
#undef SUPER_BODY
#undef REC_BODY

  // ---- epilogue: O^T is channel-major -> direct NCHW writes ----
  __syncthreads();   // full drain incl. trailing prefetches (target dead buffer)
  float* lds_t = (float*)smem;               // 128 ch x stride 33 fp32
  float* b2t   = (float*)(smem + 17408);     // [c][12], zero-padded
  for (int idx = tid; idx < 1536; idx += 512){
    int cc = idx / 12, ee = idx - cc * 12;
    float v = (ee < 11) ? b2[ee * 128 + cc] : 0.f;
    b2t[idx] = v;
    if (v != 0.f) atomicOr(&b2f, 1);   // local b2-nonzero flag (no global pass)
  }
  __syncthreads();
  int b2nz = b2f;

  #pragma unroll 1
  for (int h = 0; h < 8; ++h){
    __syncthreads();
    if (w == h){
      #pragma unroll
      for (int ct = 0; ct < 4; ++ct)
        #pragma unroll
        for (int r = 0; r < 16; ++r)
          lds_t[(ct * 32 + (r & 3) + 8 * (r >> 2) + hi4) * 33 + l31] = facc[ct][r];
    }
    __syncthreads();
    int c = tid >> 2, p8 = (tid & 3) << 3;
    int pixg = pix0 + h * 32 + p8;
    size_t base = (size_t)(pixg >> 14) * CHW_ + (size_t)c * HW_ + (pixg & 16383);
    float av[8];
    #pragma unroll
    for (int k = 0; k < 8; ++k) av[k] = lds_t[c * 33 + p8 + k];
    if (b2nz){
      #pragma unroll
      for (int k = 0; k < 8; ++k){
        const float* mr = mask + (size_t)(pixg + k) * 11;
        #pragma unroll
        for (int e = 0; e < 11; ++e) av[k] = fmaf(mr[e], b2t[c * 12 + e], av[k]);
      }
    }
    float4 xv0 = *(const float4*)(x + base);
    float4 xv1 = *(const float4*)(x + base + 4);
    float4 o0 = {av[0] + xv0.x, av[1] + xv0.y, av[2] + xv0.z, av[3] + xv0.w};
    float4 o1 = {av[4] + xv1.x, av[5] + xv1.y, av[6] + xv1.z, av[7] + xv1.w};
    *(float4*)(y + base) = o0;
    *(float4*)(y + base + 4) = o1;
  }
}

// ---------------- aux-loss finalizer (needs all blocks' atomics complete) ------
__global__ __launch_bounds__(64) void k_aux(const float* __restrict__ aux,
                                            float* __restrict__ y){
  if (threadIdx.x == 0){
    float s = 0.f;
    const float invN = 1.0f / (float)N_;
    for (int e = 0; e < E_; ++e)
      s += (aux[e] * invN) * (aux[E_ + e] * invN);
    y[(size_t)N_ * C_] = (float)E_ * s;
  }
}

extern "C" void kernel_launch(void* const* d_in, const int* in_sizes, int n_in,
                              void* d_out, int out_size, void* d_ws, size_t ws_size,
                              hipStream_t stream){
  const float* x  = (const float*)d_in[0];
  const float* gw = (const float*)d_in[1];
  const float* gb = (const float*)d_in[2];
  const float* w1 = (const float*)d_in[3];
  const float* b1 = (const float*)d_in[4];
  const float* w2 = (const float*)d_in[5];
  const float* b2 = (const float*)d_in[6];
  float* y = (float*)d_out;
  char* ws = (char*)d_ws;

  unsigned short* xcl  = (unsigned short*)ws;                   // 16,777,216 B
  unsigned short* wimg = (unsigned short*)(ws + 16777216);      //  2,883,584 B
  float* mask   = (float*)(ws + 19660800);                      //  2,883,584 B
  float* auxsum = (float*)(ws + 22544384);                      //         96 B
  unsigned short* b1h  = (unsigned short*)(ws + 22544480);      //     11,264 B

  hipLaunchKernelGGL(k_convert, dim3(726), dim3(256), 0, stream, w1, w2, b1, wimg, b1h, auxsum);
  hipLaunchKernelGGL(k_ffn,     dim3(256), dim3(512), 0, stream,
                     x, gw, gb, xcl, mask, wimg, b1h, b2, auxsum, y);
  hipLaunchKernelGGL(k_aux,     dim3(1),   dim3(64),  0, stream, auxsum, y);
}

// Round 9
// 330.003 us; speedup vs baseline: 1.0014x; 1.0014x over previous
//
#include <hip/hip_runtime.h>
#include <stdint.h>

#define C_   128
#define HW_  16384
#define CHW_ (C_*HW_)
#define N_   65536
#define E_   11
#define K_   6
#define HID_ 512

typedef __attribute__((ext_vector_type(8))) _Float16 half8;
typedef __attribute__((ext_vector_type(2))) _Float16 h2;
typedef __attribute__((ext_vector_type(2))) __fp16 fp16v2;
typedef __attribute__((ext_vector_type(16))) float float16v;
typedef __attribute__((ext_vector_type(2))) unsigned uint2v;

// async global->LDS, 16B per lane; LDS dst is wave-uniform base + lane*16
#define GLD(g, s) __builtin_amdgcn_global_load_lds( \
    (const __attribute__((address_space(1))) unsigned int*)(uintptr_t)(g), \
    (__attribute__((address_space(3))) unsigned int*)(unsigned int)(uintptr_t)(s), 16, 0, 0)

// f32x2 -> packed f16 pair (RTZ), bitcast to _Float16 vector
__device__ __forceinline__ h2 pkrtz(float a, float b){
  union { fp16v2 f; h2 h; } u;
  u.f = __builtin_amdgcn_cvt_pkrtz(a, b);
  return u.h;
}
// gelu(v)*wr on packed f16 pairs: odd deg-7 erf fit (|t|<=2.5, max err ~2.4e-3).
__device__ __forceinline__ h2 gelu2h(h2 v, h2 wr2){
  h2 u = v * v;
  h2 s = u * (h2)(_Float16)(-0.00076957f) + (h2)(_Float16)(0.0147811f);
  s = s * u + (h2)(_Float16)(-0.126434f);
  s = s * u + (h2)(_Float16)(0.795742f);
  h2 p = v * s;
  h2 phi = p * (h2)(_Float16)(0.5f) + (h2)(_Float16)(0.5f);
  return v * wr2 * phi;
}
// lane l <-> lane l^32 exchange: a' = [a_lo, b_lo], b' = [a_hi, b_hi]
__device__ __forceinline__ void pswap32(unsigned &a, unsigned &b){
#if __has_builtin(__builtin_amdgcn_permlane32_swap)
  uint2v r = __builtin_amdgcn_permlane32_swap(a, b, false, false);
  a = r.x; b = r.y;
#else
  asm volatile("v_permlane32_swap_b32 %0, %1" : "+v"(a), "+v"(b));
#endif
}

// ---------------- build MFMA-frag-ordered f16 weight image (32x32x16 frags) ----
// record i = e*16+hc (16KB): [0,8KB) W1 A-frags kc=0..7: lane l holds
//   w1[e][hc*32+(l&31)][kc*16+(l>>5)*8 + j], j=0..7
// [8KB,16KB): W2 A-frags (ct*2+kc2): lane l: w2[e][ct*32+(l&31)][hc*32+kc2*16+(l>>5)*8+j]
// plus b1h image: per record 32 f16 in hacc-register order (j-order, hi-major).
// Also zeroes the 22 aux accumulators (k_ffn atomically adds; stream-ordered).
__global__ __launch_bounds__(256) void k_convert(const float* __restrict__ w1,
                                                 const float* __restrict__ w2,
                                                 const float* __restrict__ b1,
                                                 unsigned short* __restrict__ wimg,
                                                 unsigned short* __restrict__ b1h,
                                                 float* __restrict__ auxsum){
  int t = blockIdx.x * 256 + threadIdx.x;
  if (t < 23) auxsum[t] = 0.0f;          // 22 aux accumulators (+1 spare)
  if (t >= 185856) return;
  if (t >= 180224){                       // b1h: 176 recs x 32 f16
    int t2 = t - 180224;
    int rec = t2 >> 5, j5 = t2 & 31;
    int hi = j5 >> 4, j = j5 & 15;
    int e = rec >> 4, hc = rec & 15;
    int row = (j & 3) + 8 * (j >> 2) + 4 * hi;
    union { _Float16 h; unsigned short u; } cv;
    cv.h = (_Float16)b1[e * 512 + hc * 32 + row];
    b1h[rec * 32 + j5] = cv.u;
    return;
  }
  const float* src;
  size_t dst;
  if (t < 90112){
    int e = t >> 13, hid = (t >> 4) & 511, c8 = t & 15;
    src = w1 + (size_t)t * 8;
    int rec = e * 16 + (hid >> 5);
    int kc = c8 >> 1, half = c8 & 1;
    int l = (hid & 31) | (half << 5);
    dst = (size_t)rec * 8192 + kc * 512 + l * 8;
  } else {
    int u = t - 90112;
    int e = u >> 13, cc = (u >> 6) & 127, hd8 = u & 63;
    src = w2 + (size_t)u * 8;
    int rec = e * 16 + (hd8 >> 2);
    int kc2 = (hd8 >> 1) & 1, half = hd8 & 1, ct = cc >> 5;
    int l = (cc & 31) | (half << 5);
    dst = (size_t)rec * 8192 + 4096 + (ct * 2 + kc2) * 512 + l * 8;
  }
  float4 a = *(const float4*)src, b = *(const float4*)(src + 4);
  union { _Float16 h[8]; uint4 v; } u4;
  u4.h[0] = (_Float16)a.x; u4.h[1] = (_Float16)a.y;
  u4.h[2] = (_Float16)a.z; u4.h[3] = (_Float16)a.w;
  u4.h[4] = (_Float16)b.x; u4.h[5] = (_Float16)b.y;
  u4.h[6] = (_Float16)b.z; u4.h[7] = (_Float16)b.w;
  *(uint4*)(wimg + dst) = u4.v;
}

// ---------------- fused MoE: transpose+router prologue + r7 FFN ring loop ------
// 512 thr = 8 waves; 256 px/block; grid 256 = 1 block/CU (2 waves/SIMD).
// PROLOGUE (r8 diagnosed at ~54us: xcl round-trip + scalar loads + pack pass):
//   now NO xcl buffer at all. Per 64-px round: float4 transpose-in (4x fewer
//   issues), then the two owning waves extract their Xf MFMA fragments
//   DIRECTLY from the tt LDS tile (float2 reads + pkrtz in registers --
//   bit-identical to the old xcl path), router computes mask. Removes 16.7MB
//   HBM write + read-back and the pack pass's conflicted LDS reads.
// MAIN LOOP + EPILOGUE: r7-verbatim (207us-proven). Aux finalized by k_aux.
__global__ __launch_bounds__(512, 2) void k_ffn(const float* __restrict__ x,
                                                const float* __restrict__ gw,
                                                const float* __restrict__ gb,
                                                float* __restrict__ mask,
                                                const unsigned short* __restrict__ wimg,
                                                const unsigned short* __restrict__ b1h,
                                                const float* __restrict__ b2,
                                                float* __restrict__ auxsum,
                                                float* __restrict__ y){
  __shared__ unsigned char smem[65536];
  __shared__ int b2f;
  int tid = threadIdx.x;
  int w = tid >> 6, l = tid & 63;
  int l31 = l & 31, hi = l >> 5;
  int hi4 = hi * 4;
  int pix0 = blockIdx.x * 256;
  int off = (blockIdx.x % 11) * 16;
  const unsigned char* wimgB = (const unsigned char*)wimg;
  const unsigned char* b1hB  = (const unsigned char*)b1h;

  if (tid == 0) b2f = 0;

  // X B-frags, filled by the prologue from LDS (no xcl global round-trip):
  // lane l: X^T[c = kc*16 + hi*8 + j][pix = 32w + l31]
  half8 Xf[8];

  // ======== fused prep prologue: smem hosts tt/g/stats before W staging ========
  {
    float* tt  = (float*)smem;                  // [64][130] f32 = 33,280B
    float* g   = (float*)(smem + 33280);        // [11][128] = 5,632B
    float* gbs = (float*)(smem + 38912);        // [11]
    float* ap  = (float*)(smem + 38976);        // [11]
    float* al  = (float*)(smem + 39040);        // [11]

    for (int i = tid; i < E_ * C_; i += 512) g[i] = gw[i];
    if (tid < E_){ gbs[tid] = gb[tid]; ap[tid] = 0.f; al[tid] = 0.f; }

    int myrr = w >> 1;                     // round holding this wave's pixels
    #pragma unroll 1
    for (int rr = 0; rr < 4; ++rr){
      int pixc = pix0 + rr * 64;
      const float* xb = x + (size_t)(pixc >> 14) * CHW_ + (pixc & 16383);
      __syncthreads();                    // g ready (rr=0); tt free (rr>0)
      // transpose-in: float4 along contiguous p (2048 quads / 512 thr = 4 each)
      #pragma unroll
      for (int it = 0; it < 4; ++it){
        int flat = it * 512 + tid;
        int c = flat >> 4, p4 = (flat & 15) << 2;
        float4 v = *(const float4*)(xb + (size_t)c * HW_ + p4);
        tt[(p4 + 0) * 130 + c] = v.x;
        tt[(p4 + 1) * 130 + c] = v.y;
        tt[(p4 + 2) * 130 + c] = v.z;
        tt[(p4 + 3) * 130 + c] = v.w;
      }
      __syncthreads();                    // tt ready
      // owning waves extract Xf fragments straight from tt (f32 -> pkrtz f16)
      if (myrr == rr){
        const float2* trow = (const float2*)(tt + (32 * (w & 1) + l31) * 130 + hi * 8);
        #pragma unroll
        for (int kc = 0; kc < 8; ++kc){
          union { unsigned u[4]; half8 s; } cv;
          #pragma unroll
          for (int m = 0; m < 4; ++m){
            float2 f = trow[kc * 8 + m];        // channels kc*16+hi*8+2m, +1
            union { h2 h; unsigned uu; } pv;
            pv.h = pkrtz(f.x, f.y);
            cv.u[m] = pv.uu;
          }
          Xf[kc] = cv.s;
        }
      }
      // router: threads 0..255, 4 per pixel (same wave quad), 32 ch each
      if (tid < 256){
        int p = tid >> 2, t4 = tid & 3;
        float lg[E_];
        #pragma unroll
        for (int e = 0; e < E_; ++e) lg[e] = (t4 == 0) ? gbs[e] : 0.f;
        const float2* ttrow = (const float2*)(tt + p * 130 + t4 * 32);
        #pragma unroll 4
        for (int j2 = 0; j2 < 16; ++j2){
          float2 xv = ttrow[j2];
          #pragma unroll
          for (int e = 0; e < E_; ++e){
            float2 gv = *(const float2*)(g + e * C_ + t4 * 32 + j2 * 2);
            lg[e] = fmaf(xv.x, gv.x, lg[e]);
            lg[e] = fmaf(xv.y, gv.y, lg[e]);
          }
        }
        #pragma unroll
        for (int e = 0; e < E_; ++e){
          lg[e] += __shfl_xor(lg[e], 1, 64);
          lg[e] += __shfl_xor(lg[e], 2, 64);
        }
        float mx = lg[0];
        #pragma unroll
        for (int e = 1; e < E_; ++e) mx = fmaxf(mx, lg[e]);
        float pr[E_]; float s = 0.f;
        #pragma unroll
        for (int e = 0; e < E_; ++e){ pr[e] = expf(lg[e] - mx); s += pr[e]; }
        float inv = 1.0f / s;
        #pragma unroll
        for (int e = 0; e < E_; ++e) pr[e] *= inv;

        unsigned selmask = 0; float wsum = 0.f;
        for (int k = 0; k < K_; ++k){
          float bv = -1.f; int bi = 0;
          #pragma unroll
          for (int e = 0; e < E_; ++e){
            bool better = (((selmask >> e) & 1u) == 0u) && (pr[e] > bv);
            bv = better ? pr[e] : bv;
            bi = better ? e : bi;
          }
          selmask |= 1u << bi; wsum += bv;
        }
        float invw = 1.0f / wsum;
        if (t4 == 0){
          int pix = pixc + p;
          #pragma unroll
          for (int e = 0; e < E_; ++e){
            bool sel = (selmask >> e) & 1u;
            mask[(size_t)pix * E_ + e] = sel ? pr[e] * invw : 0.f;
            atomicAdd(&ap[e], pr[e]);
            if (sel) atomicAdd(&al[e], 1.0f);
          }
        }
      }
    }
    __syncthreads();                      // all tt reads done; ap/al final
    if (tid < E_){
      atomicAdd(&auxsum[tid], ap[tid]);         // device-scope, zeroed by k_convert
      atomicAdd(&auxsum[E_ + tid], al[tid]);
    }
  }
  // ======== end prologue; smem now free for W double-buffer ====================

  uint4 bhA[4], bhB[4];
  const size_t mrow = (size_t)(pix0 + w * 32 + l31) * 11;

  // prologue: stage super-iter 0 (records off, off+1) into buffer 0.
  // GLDs first, then bias loads (vmcnt-order discipline).
  {
    #pragma unroll
    for (int k = 0; k < 2; ++k){
      int rec = off + k;
      const unsigned char* gs = wimgB + (size_t)rec * 16384 + w * 2048 + l * 16;
      unsigned char* dst = smem + k * 16384 + w * 2048;
      GLD(gs, dst);
      GLD(gs + 1024, dst + 1024);
    }
    #pragma unroll
    for (int k = 0; k < 2; ++k){
      const unsigned char* bp = b1hB + (off + k) * 64 + hi * 32;
      bhA[2 * k]     = *(const uint4*)(bp);
      bhA[2 * k + 1] = *(const uint4*)(bp + 16);
    }
  }
  // routing-weight prefetch pipeline: wrn holds expert (off>>4)'s weight
  // (mask written by this block's own router; first global touch -> no stale L1)
  float wrn = mask[mrow + (off >> 4)];
  __syncthreads();   // full drain: buffer 0 + regs ready

  float16v facc[4];
  #pragma unroll
  for (int ct = 0; ct < 4; ++ct) facc[ct] = (float16v)0.0f;
  h2 wr2 = (h2)(_Float16)0.0f;

  // one record's compute: GEMM1(LDS W1) -> gelu/pack/pswap -> GEMM2(LDS W2)
#define REC_BODY(WB, BH0, BH1)                                                      \
  {                                                                                 \
    float16v hacc_ = (float16v)0.0f;                                                \
    _Pragma("unroll")                                                               \
    for (int kc_ = 0; kc_ < 8; ++kc_){                                              \
      half8 a_ = *(const half8*)((WB) + kc_ * 1024 + l * 16);                       \
      hacc_ = __builtin_amdgcn_mfma_f32_32x32x16_f16(a_, Xf[kc_], hacc_, 0, 0, 0);  \
    }                                                                               \
    union { uint4 v[2]; h2 h[8]; } bu_;                                             \
    bu_.v[0] = BH0; bu_.v[1] = BH1;                                                 \
    unsigned pd_[8];                                                                \
    _Pragma("unroll")                                                               \
    for (int k_ = 0; k_ < 8; ++k_){                                                 \
      h2 v_ = pkrtz(hacc_[2 * k_], hacc_[2 * k_ + 1]);                              \
      v_ = v_ + bu_.h[k_];                                                          \
      union { h2 h; unsigned u; } g_;                                               \
      g_.h = gelu2h(v_, wr2);                                                       \
      pd_[k_] = g_.u;                                                               \
    }                                                                               \
    pswap32(pd_[0], pd_[2]); pswap32(pd_[1], pd_[3]);                               \
    pswap32(pd_[4], pd_[6]); pswap32(pd_[5], pd_[7]);                               \
    union { unsigned u[4]; half8 s; } cv0_, cv1_;                                   \
    cv0_.u[0] = pd_[0]; cv0_.u[1] = pd_[1]; cv0_.u[2] = pd_[2]; cv0_.u[3] = pd_[3]; \
    cv1_.u[0] = pd_[4]; cv1_.u[1] = pd_[5]; cv1_.u[2] = pd_[6]; cv1_.u[3] = pd_[7]; \
    _Pragma("unroll")                                                               \
    for (int ct_ = 0; ct_ < 4; ++ct_){                                              \
      half8 a0_ = *(const half8*)((WB) + 8192 + (ct_ * 2 + 0) * 1024 + l * 16);     \
      half8 a1_ = *(const half8*)((WB) + 8192 + (ct_ * 2 + 1) * 1024 + l * 16);     \
      facc[ct_] = __builtin_amdgcn_mfma_f32_32x32x16_f16(a0_, cv0_.s, facc[ct_], 0, 0, 0); \
      facc[ct_] = __builtin_amdgcn_mfma_f32_32x32x16_f16(a1_, cv1_.s, facc[ct_], 0, 0, 0); \
    }                                                                               \
  }

#define SUPER_BODY(J, BHC, BHL)                                                     \
  {                                                                                 \
    asm volatile("s_waitcnt vmcnt(4)" ::: "memory");                                \
    __builtin_amdgcn_s_barrier();                                                   \
    __builtin_amdgcn_sched_barrier(0);                                              \
    /* prefetch super-iter J+1: 4 GLDs FIRST, then 4 bias loads; wrap benign */     \
    {                                                                               \
      unsigned char* dbuf_ = smem + ((((J) + 1) & 1) << 15);                        \
      _Pragma("unroll")                                                             \
      for (int k_ = 0; k_ < 2; ++k_){                                               \
        int rn_ = 2 * (J) + 2 + k_ + off; if (rn_ >= 176) rn_ -= 176;               \
        const unsigned char* gs_ = wimgB + (size_t)rn_ * 16384 + w * 2048 + l * 16; \
        unsigned char* dst_ = dbuf_ + k_ * 16384 + w * 2048;                        \
        GLD(gs_, dst_);                                                             \
        GLD(gs_ + 1024, dst_ + 1024);                                               \
      }                                                                             \
      __builtin_amdgcn_sched_barrier(0);                                            \
      _Pragma("unroll")                                                             \
      for (int k_ = 0; k_ < 2; ++k_){                                               \
        int rn_ = 2 * (J) + 2 + k_ + off; if (rn_ >= 176) rn_ -= 176;               \
        const unsigned char* bp_ = b1hB + rn_ * 64 + hi * 32;                       \
        BHL[2 * k_]     = *(const uint4*)(bp_);                                     \
        BHL[2 * k_ + 1] = *(const uint4*)(bp_ + 16);                                \
      }                                                                             \
    }                                                                               \
    __builtin_amdgcn_sched_barrier(0);                                              \
    if (((J) & 7) == 0){   /* expert switch every 8 super-iters (uniform) */        \
      _Float16 wh_ = (_Float16)wrn;                                                 \
      wr2 = (h2){wh_, wh_};                                                         \
      int rn_ = 2 * (J) + 16 + off; if (rn_ >= 176) rn_ -= 176;                     \
      wrn = mask[mrow + (rn_ >> 4)];                                                \
    }                                                                               \
    const unsigned char* wb_ = smem + (((J) & 1) << 15);                            \
    REC_BODY(wb_, BHC[0], BHC[1]);                                                  \
    REC_BODY(wb_ + 16384, BHC[2], BHC[3]);                                          \
  }

  #pragma unroll 1
  for (int jj = 0; jj < 44; ++jj){
    SUPER_BODY(2 * jj,     bhA, bhB);
    SUPER_BODY(2 * jj + 1, bhB, bhA);
  }
#undef SUPER_BODY
#undef REC_BODY

  // ---- epilogue: O^T is channel-major -> direct NCHW writes ----
  __syncthreads();   // full drain incl. trailing prefetches (target dead buffer)
  float* lds_t = (float*)smem;               // 128 ch x stride 33 fp32
  float* b2t   = (float*)(smem + 17408);     // [c][12], zero-padded
  for (int idx = tid; idx < 1536; idx += 512){
    int cc = idx / 12, ee = idx - cc * 12;
    float v = (ee < 11) ? b2[ee * 128 + cc] : 0.f;
    b2t[idx] = v;
    if (v != 0.f) atomicOr(&b2f, 1);   // local b2-nonzero flag (no global pass)
  }
  __syncthreads();
  int b2nz = b2f;

  #pragma unroll 1
  for (int h = 0; h < 8; ++h){
    __syncthreads();
    if (w == h){
      #pragma unroll
      for (int ct = 0; ct < 4; ++ct)
        #pragma unroll
        for (int r = 0; r < 16; ++r)
          lds_t[(ct * 32 + (r & 3) + 8 * (r >> 2) + hi4) * 33 + l31] = facc[ct][r];
    }
    __syncthreads();
    int c = tid >> 2, p8 = (tid & 3) << 3;
    int pixg = pix0 + h * 32 + p8;
    size_t base = (size_t)(pixg >> 14) * CHW_ + (size_t)c * HW_ + (pixg & 16383);
    float av[8];
    #pragma unroll
    for (int k = 0; k < 8; ++k) av[k] = lds_t[c * 33 + p8 + k];
    if (b2nz){
      #pragma unroll
      for (int k = 0; k < 8; ++k){
        const float* mr = mask + (size_t)(pixg + k) * 11;
        #pragma unroll
        for (int e = 0; e < 11; ++e) av[k] = fmaf(mr[e], b2t[c * 12 + e], av[k]);
      }
    }
    float4 xv0 = *(const float4*)(x + base);
    float4 xv1 = *(const float4*)(x + base + 4);
    float4 o0 = {av[0] + xv0.x, av[1] + xv0.y, av[2] + xv0.z, av[3] + xv0.w};
    float4 o1 = {av[4] + xv1.x, av[5] + xv1.y, av[6] + xv1.z, av[7] + xv1.w};
    *(float4*)(y + base) = o0;
    *(float4*)(y + base + 4) = o1;
  }
}

// ---------------- aux-loss finalizer (needs all blocks' atomics complete) ------
__global__ __launch_bounds__(64) void k_aux(const float* __restrict__ aux,
                                            float* __restrict__ y){
  if (threadIdx.x == 0){
    float s = 0.f;
    const float invN = 1.0f / (float)N_;
    for (int e = 0; e < E_; ++e)
      s += (aux[e] * invN) * (aux[E_ + e] * invN);
    y[(size_t)N_ * C_] = (float)E_ * s;
  }
}

extern "C" void kernel_launch(void* const* d_in, const int* in_sizes, int n_in,
                              void* d_out, int out_size, void* d_ws, size_t ws_size,
                              hipStream_t stream){
  const float* x  = (const float*)d_in[0];
  const float* gw = (const float*)d_in[1];
  const float* gb = (const float*)d_in[2];
  const float* w1 = (const float*)d_in[3];
  const float* b1 = (const float*)d_in[4];
  const float* w2 = (const float*)d_in[5];
  const float* b2 = (const float*)d_in[6];
  float* y = (float*)d_out;
  char* ws = (char*)d_ws;

  unsigned short* wimg = (unsigned short*)ws;                   //  2,883,584 B
  float* mask   = (float*)(ws + 2883584);                       //  2,883,584 B
  float* auxsum = (float*)(ws + 5767168);                       //         96 B
  unsigned short* b1h  = (unsigned short*)(ws + 5767264);       //     11,264 B

  hipLaunchKernelGGL(k_convert, dim3(726), dim3(256), 0, stream, w1, w2, b1, wimg, b1h, auxsum);
  hipLaunchKernelGGL(k_ffn,     dim3(256), dim3(512), 0, stream,
                     x, gw, gb, mask, wimg, b1h, b2, auxsum, y);
  hipLaunchKernelGGL(k_aux,     dim3(1),   dim3(64),  0, stream, auxsum, y);
}